// Round 1
// baseline (302.026 us; speedup 1.0000x reference)
//
#include <hip/hip_runtime.h>

// B=128, C_IN=128, C_HID=256, C_OUT=128, H*W=1600, E=8, TOP_K=2.
#define CIN   128
#define CHID  256
#define COUT  128
#define HWPX  1600

typedef __attribute__((ext_vector_type(8))) short bf16x8;  // 8 bf16 = 4 VGPRs
typedef __attribute__((ext_vector_type(4))) float f32x4;   // MFMA C/D

__device__ __forceinline__ unsigned short f2bf(float f) {
  // round-to-nearest-even fp32 -> bf16
  unsigned int u = __builtin_bit_cast(unsigned int, f);
  u += 0x7FFFu + ((u >> 16) & 1u);
  return (unsigned short)(u >> 16);
}
__device__ __forceinline__ unsigned int pack_bf2(float a, float b) {
  return (unsigned int)f2bf(a) | ((unsigned int)f2bf(b) << 16);
}
__device__ __forceinline__ unsigned int silu_gate_pk(float a, float b, float g) {
  const float sa = g * a / (1.0f + __expf(-a));
  const float sb = g * b / (1.0f + __expf(-b));
  return pack_bf2(sa, sb);
}

// fp32->bf16 convert into LDS-slice-ordered, swizzled layouts.
// W1b: [e][grp][512 chunks][8], chunk pos p = r*16 + ((c + r) & 15), where
//   r = GEMM row-position in the 32-row slice (h-trick permuted:
//   position mt*16+row holds true ch = (row>>2)*8 + (row&3) + mt*4),
//   c = cin chunk (8 cin each).
// W2b: [e][grp][512 chunks][8], chunk pos p = co*4 + ((c + co + (co>>2)) & 3),
//   c = ch chunk within the 32-ch group.
// The rotations make the kernel's strided ds_read_b128 patterns conflict-free.
__global__ __launch_bounds__(256) void convert_w_kernel(
    const float* __restrict__ W1, const float* __restrict__ W2,
    unsigned short* __restrict__ W1b, unsigned short* __restrict__ W2b) {
  const int i   = blockIdx.x * 256 + threadIdx.x;   // 0 .. 262143
  const int j   = i & 7;
  const int p   = (i >> 3) & 511;
  const int grp = (i >> 12) & 7;
  const int e   = i >> 15;
  {
    const int r   = p >> 4;
    const int c   = ((p & 15) - r) & 15;
    const int row = r & 15, mt = r >> 4;
    const int ch  = grp * 32 + ((row >> 2) << 3) + (row & 3) + (mt << 2);
    W1b[i] = f2bf(W1[(e * CHID + ch) * CIN + c * 8 + j]);
  }
  {
    const int co = p >> 2;
    const int c  = ((p & 3) - co - (co >> 2)) & 3;
    const int ch = grp * 32 + c * 8 + j;
    W2b[i] = f2bf(W2[(e * COUT + co) * CHID + ch]);
  }
}

__global__ __launch_bounds__(256, 2) void moe_kernel(
    const float* __restrict__ x, const float* __restrict__ wts,
    const int* __restrict__ idx, const unsigned short* __restrict__ W1,
    const float* __restrict__ b1, const unsigned short* __restrict__ W2,
    const float* __restrict__ b2, float* __restrict__ out) {
  // 80 KB total -> exactly 2 blocks/CU on 160 KB LDS.
  // [0,32768): x tiles, 4 waves x 16 KB (swizzled chunks)
  // [32768,36864): W1 slice (8 KB)   [36864,40960): W2 slice (8 KB)
  __shared__ __align__(16) unsigned short lds[40960];

  const int tid  = threadIdx.x;
  const int wave = tid >> 6;
  const int lane = tid & 63;
  const int q    = lane >> 4;
  const int r16  = lane & 15;

  const int  b     = blockIdx.x / 7;
  const int  t4    = blockIdx.x % 7;
  const int  tile  = t4 * 4 + wave;          // 0..27 (25..27 idle)
  const bool valid = (tile < 25);
  const int  tileC = valid ? tile : 24;      // clamp for safe addressing
  const int  px0   = tileC * 64;

  unsigned short* xw = &lds[wave * 8192];    // this wave's 16 KB x region

  // ---- stage x tile (within-wave producer/consumer -> no barrier needed)
  {
    const float* xb = x + (long)b * CIN * HWPX + px0 + lane;
#pragma unroll 4
    for (int c = 0; c < 16; ++c) {
      float v[8];
#pragma unroll
      for (int jj = 0; jj < 8; ++jj) v[jj] = xb[(long)(c * 8 + jj) * HWPX];
      union { bf16x8 w; unsigned int u[4]; } t;
#pragma unroll
      for (int d = 0; d < 4; ++d) t.u[d] = pack_bf2(v[2 * d], v[2 * d + 1]);
      const int slot = (c + lane) & 15;      // rotation swizzle
      *reinterpret_cast<bf16x8*>(&xw[(lane * 16 + slot) * 8]) = t.w;
    }
  }

  const int   e0 = idx[b * 2 + 0], e1 = idx[b * 2 + 1];
  const float g0 = wts[b * 2 + 0], g1 = wts[b * 2 + 1];

  f32x4 accO[8][4];
#pragma unroll
  for (int mt = 0; mt < 8; ++mt)
#pragma unroll
    for (int nt = 0; nt < 4; ++nt) accO[mt][nt] = (f32x4){0.f, 0.f, 0.f, 0.f};

  const uint4* w1g = reinterpret_cast<const uint4*>(W1);
  const uint4* w2g = reinterpret_cast<const uint4*>(W2);
  uint4* ws1 = reinterpret_cast<uint4*>(&lds[32768]);
  uint4* ws2 = reinterpret_cast<uint4*>(&lds[36864]);

  // preload slices for gs=0 into registers
  uint4 p1a, p1b, p2a, p2b;
  {
    const long base = (long)e0 * 4096 + tid;   // (e*8+grp)*512 + tid, grp=0
    p1a = w1g[base]; p1b = w1g[base + 256];
    p2a = w2g[base]; p2b = w2g[base + 256];
  }

  for (int gs = 0; gs < 16; ++gs) {
    const int   slot = gs >> 3;
    const int   grp  = gs & 7;
    const int   e    = slot ? e1 : e0;
    const float g    = slot ? g1 : g0;

    __syncthreads();                         // prior group done reading ws*
    ws1[tid] = p1a; ws1[tid + 256] = p1b;
    ws2[tid] = p2a; ws2[tid + 256] = p2b;
    __syncthreads();                         // slice gs visible

    if (gs < 15) {                           // prefetch next slice (hidden by compute)
      const int  gs2  = gs + 1;
      const int  e2   = (gs2 >> 3) ? e1 : e0;
      const long base = (long)e2 * 4096 + (long)(gs2 & 7) * 512 + tid;
      p1a = w1g[base]; p1b = w1g[base + 256];
      p2a = w2g[base]; p2b = w2g[base + 256];
    }

    // ---- GEMM1: 32 hidden ch (permuted rows), K = 128
    f32x4 aA[4], aB[4];
#pragma unroll
    for (int nt = 0; nt < 4; ++nt) {
      aA[nt] = (f32x4){0.f, 0.f, 0.f, 0.f};
      aB[nt] = (f32x4){0.f, 0.f, 0.f, 0.f};
    }
#pragma unroll
    for (int ks = 0; ks < 4; ++ks) {
      const int slotw = (ks * 4 + q + r16) & 15;   // same rotation for R0/R0+16
      const bf16x8 w0 = *reinterpret_cast<const bf16x8*>(
          &lds[32768 + (r16 * 16 + slotw) * 8]);
      const bf16x8 w1v = *reinterpret_cast<const bf16x8*>(
          &lds[32768 + ((r16 + 16) * 16 + slotw) * 8]);
#pragma unroll
      for (int nt = 0; nt < 4; ++nt) {
        const int px = nt * 16 + r16;
        const bf16x8 xf = *reinterpret_cast<const bf16x8*>(
            &xw[(px * 16 + ((ks * 4 + q + px) & 15)) * 8]);
        aA[nt] = __builtin_amdgcn_mfma_f32_16x16x32_bf16(w0, xf, aA[nt], 0, 0, 0);
        aB[nt] = __builtin_amdgcn_mfma_f32_16x16x32_bf16(w1v, xf, aB[nt], 0, 0, 0);
      }
    }

    // ---- bias + SiLU + gate -> GEMM2 B-fragments (true ch = base + q*8 + j)
    const float* b1e = b1 + e * CHID + grp * 32;
    const f32x4 bA = *reinterpret_cast<const f32x4*>(&b1e[q * 8]);
    const f32x4 bB = *reinterpret_cast<const f32x4*>(&b1e[q * 8 + 4]);
    union { bf16x8 v; unsigned int u[4]; } h[4];
#pragma unroll
    for (int nt = 0; nt < 4; ++nt) {
      h[nt].u[0] = silu_gate_pk(aA[nt][0] + bA[0], aA[nt][1] + bA[1], g);
      h[nt].u[1] = silu_gate_pk(aA[nt][2] + bA[2], aA[nt][3] + bA[3], g);
      h[nt].u[2] = silu_gate_pk(aB[nt][0] + bB[0], aB[nt][1] + bB[1], g);
      h[nt].u[3] = silu_gate_pk(aB[nt][2] + bB[2], aB[nt][3] + bB[3], g);
    }

    // ---- GEMM2 partial-K (this 32-ch chunk)
#pragma unroll
    for (int mt = 0; mt < 8; ++mt) {
      const int co = mt * 16 + r16;
      const bf16x8 w2v = *reinterpret_cast<const bf16x8*>(
          &lds[36864 + (co * 4 + ((q + co + (co >> 2)) & 3)) * 8]);
#pragma unroll
      for (int nt = 0; nt < 4; ++nt)
        accO[mt][nt] = __builtin_amdgcn_mfma_f32_16x16x32_bf16(w2v, h[nt].v, accO[mt][nt], 0, 0, 0);
    }
  }

  // ---- epilogue: per-wave LDS transpose (reuse dead x region; DS FIFO
  //      ordering within a wave -> no barriers), coalesced 16 B stores.
  float* eb = reinterpret_cast<float*>(xw);  // [16][68] f32 = 4352 B <= 16 KB
  const float* b2e0 = b2 + e0 * COUT;
  const float* b2e1 = b2 + e1 * COUT;
  const int  coR   = lane >> 2;              // 0..15
  const int  qtr   = lane & 3;
  const long orow0 = (long)b * COUT * HWPX + px0 + qtr * 16;
#pragma unroll
  for (int mt = 0; mt < 8; ++mt) {
    const int coW = q * 4;
    const f32x4 bias = g0 * (*reinterpret_cast<const f32x4*>(&b2e0[mt * 16 + coW])) +
                       g1 * (*reinterpret_cast<const f32x4*>(&b2e1[mt * 16 + coW]));
#pragma unroll
    for (int nt = 0; nt < 4; ++nt) {
      const f32x4 v = accO[mt][nt] + bias;
#pragma unroll
      for (int rr = 0; rr < 4; ++rr)
        eb[(coW + rr) * 68 + nt * 16 + r16] = v[rr];
    }
    if (valid) {
      const long orow = orow0 + (long)(mt * 16 + coR) * HWPX;
#pragma unroll
      for (int i4 = 0; i4 < 4; ++i4) {
        const float4 ov = *reinterpret_cast<const float4*>(
            &eb[coR * 68 + qtr * 16 + i4 * 4]);
        *reinterpret_cast<float4*>(&out[orow + i4 * 4]) = ov;
      }
    }
  }
}

extern "C" void kernel_launch(void* const* d_in, const int* in_sizes, int n_in,
                              void* d_out, int out_size, void* d_ws, size_t ws_size,
                              hipStream_t stream) {
  const float* x   = (const float*)d_in[0];
  const float* wts = (const float*)d_in[1];
  const int*   idx = (const int*)d_in[2];
  const float* W1  = (const float*)d_in[3];
  const float* b1  = (const float*)d_in[4];
  const float* W2  = (const float*)d_in[5];
  const float* b2  = (const float*)d_in[6];
  float* out = (float*)d_out;

  unsigned short* W1b = (unsigned short*)d_ws;                    // 8*8*512*8
  unsigned short* W2b = (unsigned short*)d_ws + (8 * CHID * CIN); // same size

  convert_w_kernel<<<262144 / 256, 256, 0, stream>>>(W1, W2, W1b, W2b);
  moe_kernel<<<128 * 7, 256, 0, stream>>>(x, wts, idx, W1b, b1, W2b, b2, out);
}